// Round 1
// baseline (2496.267 us; speedup 1.0000x reference)
//
#include <hip/hip_runtime.h>

#define BATCH 256
#define SEQ   128
#define EDIM  512
#define HDIM  1024
#define GDIM  4096   // 4*H
#define KCAT  1536   // E + H
#define PDIM  512
#define ODIM  6

typedef _Float16 f16;
typedef _Float16 f16x8 __attribute__((ext_vector_type(8)));
typedef float f32x4 __attribute__((ext_vector_type(4)));

// ---------------- workspace layout (bytes) ----------------
static const size_t XS_OFF    = 0;                                      // f16 [SEQ][BATCH][EDIM]
static const size_t WCAT_OFF  = XS_OFF    + (size_t)SEQ*BATCH*EDIM*2;   // f16 [GDIM][KCAT]
static const size_t WB_OFF    = WCAT_OFF  + (size_t)GDIM*KCAT*2;        // f16 [GDIM][EDIM]
static const size_t BIASF_OFF = WB_OFF    + (size_t)GDIM*EDIM*2;        // f32 [GDIM]
static const size_t BIASB_OFF = BIASF_OFF + (size_t)GDIM*4;             // f32 [GDIM]
static const size_t CF_OFF    = BIASB_OFF + (size_t)GDIM*4;             // f32 [BATCH][HDIM]
static const size_t CB_OFF    = CF_OFF    + (size_t)BATCH*HDIM*4;       // f32 [BATCH][HDIM]
static const size_t HPING_OFF = CB_OFF    + (size_t)BATCH*HDIM*4;       // f16 [BATCH][HDIM]
static const size_t HPONG_OFF = HPING_OFF + (size_t)BATCH*HDIM*2;       // f16
static const size_t HBD_OFF   = HPONG_OFF + (size_t)BATCH*HDIM*2;       // f16 (dump)
static const size_t HCAT_OFF  = HBD_OFF   + (size_t)BATCH*HDIM*2;       // f32 [BATCH][2*HDIM]
static const size_t P_OFF     = HCAT_OFF  + (size_t)BATCH*2*HDIM*4;     // f32 [BATCH][PDIM]

// ---------------- embedding gather + tanh -> f16 ----------------
__global__ __launch_bounds__(64) void embed_k(const int* __restrict__ seq,
                                              const float* __restrict__ emb,
                                              f16* __restrict__ xs) {
  int bid = blockIdx.x;                 // t*256 + b
  int t = bid >> 8, b = bid & 255;
  int tok = seq[b * SEQ + t];
  const float* src = emb + (size_t)tok * EDIM + threadIdx.x * 8;
  f16* dst = xs + (size_t)bid * EDIM + threadIdx.x * 8;
  float4 v0 = *(const float4*)src;
  float4 v1 = *(const float4*)(src + 4);
  f16x8 o;
  o[0] = (f16)tanhf(v0.x); o[1] = (f16)tanhf(v0.y);
  o[2] = (f16)tanhf(v0.z); o[3] = (f16)tanhf(v0.w);
  o[4] = (f16)tanhf(v1.x); o[5] = (f16)tanhf(v1.y);
  o[6] = (f16)tanhf(v1.z); o[7] = (f16)tanhf(v1.w);
  *(f16x8*)dst = o;
}

// ---------------- weight conversions ----------------
__global__ __launch_bounds__(256) void wcat_k(const float* __restrict__ wih,
                                              const float* __restrict__ whh,
                                              f16* __restrict__ wcat) {
  int idx = blockIdx.x * 256 + threadIdx.x;    // chunk of 8, KCAT/8 = 192 per row
  int n = idx / 192, c8 = (idx % 192) * 8;
  const float* src = (c8 < EDIM) ? (wih + (size_t)n * EDIM + c8)
                                 : (whh + (size_t)n * HDIM + (c8 - EDIM));
  float4 v0 = *(const float4*)src;
  float4 v1 = *(const float4*)(src + 4);
  f16x8 o;
  o[0] = (f16)v0.x; o[1] = (f16)v0.y; o[2] = (f16)v0.z; o[3] = (f16)v0.w;
  o[4] = (f16)v1.x; o[5] = (f16)v1.y; o[6] = (f16)v1.z; o[7] = (f16)v1.w;
  *(f16x8*)(wcat + (size_t)n * KCAT + c8) = o;
}

__global__ __launch_bounds__(256) void wb_k(const float* __restrict__ wih,
                                            f16* __restrict__ wb) {
  int idx = blockIdx.x * 256 + threadIdx.x;    // EDIM/8 = 64 chunks per row
  int n = idx >> 6, c8 = (idx & 63) * 8;
  const float* src = wih + (size_t)n * EDIM + c8;
  float4 v0 = *(const float4*)src;
  float4 v1 = *(const float4*)(src + 4);
  f16x8 o;
  o[0] = (f16)v0.x; o[1] = (f16)v0.y; o[2] = (f16)v0.z; o[3] = (f16)v0.w;
  o[4] = (f16)v1.x; o[5] = (f16)v1.y; o[6] = (f16)v1.z; o[7] = (f16)v1.w;
  *(f16x8*)(wb + (size_t)n * EDIM + c8) = o;
}

__global__ __launch_bounds__(256) void bias_k(const float* __restrict__ bih_f,
                                              const float* __restrict__ bhh_f,
                                              const float* __restrict__ bih_b,
                                              const float* __restrict__ bhh_b,
                                              float* __restrict__ biasf,
                                              float* __restrict__ biasb) {
  int i = blockIdx.x * 256 + threadIdx.x;
  if (i < GDIM) biasf[i] = bih_f[i] + bhh_f[i];
  else { int k = i - GDIM; biasb[k] = bih_b[k] + bhh_b[k]; }
}

// ---------------- fused LSTM step: gates GEMM + pointwise ----------------
// grid (4, 64): m0 = bx*64, j0 = by*16. Block = 256 threads = 4 waves.
// Output gate-tile: 64 m-rows x 64 gate-cols, where gate-col gc = g*16 + jl
// maps to weight row g*1024 + j0 + jl  (g in {i,f,g,o}).
// A (row-major, K-fastest) = [ x_t (K1 cols from A1) | h (from A2) ].
__global__ __launch_bounds__(256) void lstm_step(
    const f16* __restrict__ A1, const f16* __restrict__ A2,
    int ld2, int K1, int Ktot,
    const f16* __restrict__ W, int ldw,
    const float* __restrict__ bias,
    const float* cin, float* cout,
    f16* __restrict__ hf16, float* __restrict__ h32, int wf32)
{
  __shared__ __align__(16) f16 lsA[64 * 136];   // 64 x 128, stride padded to 136
  __shared__ __align__(16) f16 lsB[64 * 136];
  __shared__ float lsG[64 * 65];

  int tid = threadIdx.x;
  int m0 = blockIdx.x * 64;
  int j0 = blockIdx.y * 16;
  int w = tid >> 6, lane = tid & 63;
  int wm = (w >> 1) * 32, wn = (w & 1) * 32;
  int l15 = lane & 15, l4 = lane >> 4;

  f32x4 acc[2][2] = {};
  int nk = Ktot >> 7;                            // K tiles of 128

  for (int kt = 0; kt < nk; ++kt) {
    int k0 = kt << 7;
    #pragma unroll
    for (int cc = 0; cc < 4; ++cc) {             // 1024 chunks of 8 f16, 4/thread
      int idx = tid + cc * 256;
      int row = idx >> 4, c8 = (idx & 15) << 3;
      int k = k0 + c8;
      const f16* sa = (k < K1) ? (A1 + (size_t)(m0 + row) * EDIM + k)
                               : (A2 + (size_t)(m0 + row) * ld2 + (k - K1));
      *(f16x8*)&lsA[row * 136 + c8] = *(const f16x8*)sa;
      int ng = ((row >> 4) << 10) + j0 + (row & 15);   // gate*1024 + j
      *(f16x8*)&lsB[row * 136 + c8] = *(const f16x8*)(W + (size_t)ng * ldw + k);
    }
    __syncthreads();
    #pragma unroll
    for (int ks = 0; ks < 4; ++ks) {
      int ko = ks * 32 + l4 * 8;
      f16x8 a0 = *(const f16x8*)&lsA[(wm + l15) * 136 + ko];
      f16x8 a1 = *(const f16x8*)&lsA[(wm + 16 + l15) * 136 + ko];
      f16x8 b0 = *(const f16x8*)&lsB[(wn + l15) * 136 + ko];
      f16x8 b1 = *(const f16x8*)&lsB[(wn + 16 + l15) * 136 + ko];
      acc[0][0] = __builtin_amdgcn_mfma_f32_16x16x32_f16(a0, b0, acc[0][0], 0, 0, 0);
      acc[0][1] = __builtin_amdgcn_mfma_f32_16x16x32_f16(a0, b1, acc[0][1], 0, 0, 0);
      acc[1][0] = __builtin_amdgcn_mfma_f32_16x16x32_f16(a1, b0, acc[1][0], 0, 0, 0);
      acc[1][1] = __builtin_amdgcn_mfma_f32_16x16x32_f16(a1, b1, acc[1][1], 0, 0, 0);
    }
    __syncthreads();
  }

  // exchange gates through LDS so each thread sees all 4 gates of its (m,j)
  #pragma unroll
  for (int mi = 0; mi < 2; ++mi)
    #pragma unroll
    for (int ni = 0; ni < 2; ++ni) {
      int col = wn + ni * 16 + l15;              // gate-col index 0..63
      int mr = wm + mi * 16 + l4 * 4;            // C/D: row=(lane>>4)*4+reg
      #pragma unroll
      for (int r = 0; r < 4; ++r)
        lsG[(mr + r) * 65 + col] = acc[mi][ni][r];
    }
  __syncthreads();

  int jl = tid & 15, mb = tid >> 4;
  int j = j0 + jl;
  #pragma unroll
  for (int mm = 0; mm < 4; ++mm) {
    int ml = mb + mm * 16;
    int m = m0 + ml;
    float gi = lsG[ml * 65 +      jl] + bias[j];
    float gf = lsG[ml * 65 + 16 + jl] + bias[HDIM + j];
    float gg = lsG[ml * 65 + 32 + jl] + bias[2 * HDIM + j];
    float go = lsG[ml * 65 + 48 + jl] + bias[3 * HDIM + j];
    float si = 1.f / (1.f + __expf(-gi));
    float sf = 1.f / (1.f + __expf(-gf));
    float so = 1.f / (1.f + __expf(-go));
    float c  = sf * cin[m * HDIM + j] + si * tanhf(gg);
    cout[m * HDIM + j] = c;
    float h = so * tanhf(c);
    hf16[m * HDIM + j] = (f16)h;
    if (wf32) h32[(size_t)m * 2 * HDIM + j] = h;
  }
}

// ---------------- p = hcat @ Wp^T + bp  (256x2048 @ 2048x512) ----------------
__global__ __launch_bounds__(256) void proj1_k(const float* __restrict__ hcat,
                                               const float* __restrict__ Wp,
                                               const float* __restrict__ bp,
                                               float* __restrict__ p) {
  __shared__ float sA[32][65];
  __shared__ float sB[32][65];
  int tid = threadIdx.x;
  int m0 = blockIdx.x * 32, n0 = blockIdx.y * 32;
  int tm = tid >> 4, to = tid & 15;
  float a00 = 0.f, a01 = 0.f, a10 = 0.f, a11 = 0.f;
  for (int k0 = 0; k0 < 2 * HDIM; k0 += 64) {
    #pragma unroll
    for (int cc = 0; cc < 2; ++cc) {
      int idx = tid + cc * 256;
      int row = idx >> 4, c4 = (idx & 15) * 4;
      float4 va = *(const float4*)(hcat + (size_t)(m0 + row) * 2 * HDIM + k0 + c4);
      sA[row][c4] = va.x; sA[row][c4 + 1] = va.y; sA[row][c4 + 2] = va.z; sA[row][c4 + 3] = va.w;
      float4 vb = *(const float4*)(Wp + (size_t)(n0 + row) * 2 * HDIM + k0 + c4);
      sB[row][c4] = vb.x; sB[row][c4 + 1] = vb.y; sB[row][c4 + 2] = vb.z; sB[row][c4 + 3] = vb.w;
    }
    __syncthreads();
    #pragma unroll
    for (int k = 0; k < 64; ++k) {
      float x0 = sA[tm][k], x1 = sA[tm + 16][k];
      float y0 = sB[to][k], y1 = sB[to + 16][k];
      a00 += x0 * y0; a01 += x0 * y1; a10 += x1 * y0; a11 += x1 * y1;
    }
    __syncthreads();
  }
  p[(size_t)(m0 + tm) * PDIM + n0 + to]           = a00 + bp[n0 + to];
  p[(size_t)(m0 + tm) * PDIM + n0 + to + 16]      = a01 + bp[n0 + to + 16];
  p[(size_t)(m0 + tm + 16) * PDIM + n0 + to]      = a10 + bp[n0 + to];
  p[(size_t)(m0 + tm + 16) * PDIM + n0 + to + 16] = a11 + bp[n0 + to + 16];
}

// ---------------- out = sigmoid(p @ Wc^T + bc) ----------------
__global__ __launch_bounds__(64) void proj2_k(const float* __restrict__ p,
                                              const float* __restrict__ Wc,
                                              const float* __restrict__ bc,
                                              float* __restrict__ out) {
  int m = blockIdx.x, l = threadIdx.x;
  float pv[8];
  #pragma unroll
  for (int q = 0; q < 8; ++q) pv[q] = p[(size_t)m * PDIM + l + 64 * q];
  #pragma unroll
  for (int c = 0; c < ODIM; ++c) {
    float s = 0.f;
    #pragma unroll
    for (int q = 0; q < 8; ++q) s += pv[q] * Wc[c * PDIM + l + 64 * q];
    #pragma unroll
    for (int off = 32; off > 0; off >>= 1) s += __shfl_down(s, off);
    if (l == 0) out[m * ODIM + c] = 1.f / (1.f + __expf(-(s + bc[c])));
  }
}

extern "C" void kernel_launch(void* const* d_in, const int* in_sizes, int n_in,
                              void* d_out, int out_size, void* d_ws, size_t ws_size,
                              hipStream_t stream) {
  const int*   seq   = (const int*)d_in[0];
  const float* emb   = (const float*)d_in[1];
  const float* wih_f = (const float*)d_in[2];
  const float* whh_f = (const float*)d_in[3];
  const float* bih_f = (const float*)d_in[4];
  const float* bhh_f = (const float*)d_in[5];
  const float* wih_b = (const float*)d_in[6];
  const float* bih_b = (const float*)d_in[8];
  const float* bhh_b = (const float*)d_in[9];
  const float* Wp    = (const float*)d_in[10];
  const float* bp    = (const float*)d_in[11];
  const float* Wc    = (const float*)d_in[12];
  const float* bc    = (const float*)d_in[13];

  char* ws = (char*)d_ws;
  f16*   xs    = (f16*)(ws + XS_OFF);
  f16*   wcat  = (f16*)(ws + WCAT_OFF);
  f16*   wb    = (f16*)(ws + WB_OFF);
  float* biasf = (float*)(ws + BIASF_OFF);
  float* biasb = (float*)(ws + BIASB_OFF);
  float* cf    = (float*)(ws + CF_OFF);
  float* cb    = (float*)(ws + CB_OFF);
  f16*   hping = (f16*)(ws + HPING_OFF);
  f16*   hpong = (f16*)(ws + HPONG_OFF);
  f16*   hbd   = (f16*)(ws + HBD_OFF);
  float* hcat  = (float*)(ws + HCAT_OFF);
  float* p     = (float*)(ws + P_OFF);

  // zero c_f, c_b, h_ping (contiguous region)
  hipMemsetAsync(ws + CF_OFF, 0,
                 (size_t)BATCH * HDIM * 4 * 2 + (size_t)BATCH * HDIM * 2, stream);

  wcat_k<<<(GDIM * KCAT / 8) / 256, 256, 0, stream>>>(wih_f, whh_f, wcat);
  wb_k<<<(GDIM * EDIM / 8) / 256, 256, 0, stream>>>(wih_b, wb);
  bias_k<<<(2 * GDIM) / 256, 256, 0, stream>>>(bih_f, bhh_f, bih_b, bhh_b, biasf, biasb);
  embed_k<<<SEQ * BATCH, 64, 0, stream>>>(seq, emb, xs);

  // backward reduces to ONE step on xs[0] with zero state (only b_hs[0] is used)
  lstm_step<<<dim3(4, 64), 256, 0, stream>>>(xs, xs, EDIM, EDIM, EDIM,
      wb, EDIM, biasb, cb, cb, hbd, hcat + HDIM, 1);

  // forward scan: 128 sequential fused steps
  for (int t = 0; t < SEQ; ++t) {
    const f16* hin = (t & 1) ? hpong : hping;
    f16* hout = (t & 1) ? hping : hpong;
    lstm_step<<<dim3(4, 64), 256, 0, stream>>>(
        xs + (size_t)t * BATCH * EDIM, hin, HDIM, EDIM, KCAT,
        wcat, KCAT, biasf, cf, cf, hout, hcat, (t == SEQ - 1) ? 1 : 0);
  }

  proj1_k<<<dim3(8, 16), 256, 0, stream>>>(hcat, Wp, bp, p);
  proj2_k<<<BATCH, 64, 0, stream>>>(p, Wc, bc, (float*)d_out);
}